// Round 3
// baseline (2598.232 us; speedup 1.0000x reference)
//
#include <hip/hip_runtime.h>
#include <hip/hip_bf16.h>
#include <math.h>
#include <string.h>

#define L_TOK 16384
#define D_INP 256
#define D_MOD 768
#define D_FF  1536
#define N_LAYER 8
#define S_T 64
#define S_G 256
#define EPSV 1e-5f

typedef short bf16x8 __attribute__((ext_vector_type(8)));
typedef float f32x4 __attribute__((ext_vector_type(4)));
typedef __hip_bfloat16 bf16;
typedef unsigned int u32;
typedef unsigned short u16;

__device__ __forceinline__ float fsigmoid(float z) { return 1.0f / (1.0f + __expf(-z)); }

__device__ __forceinline__ u16 f2bf(float f) {
  __hip_bfloat16 h = __float2bfloat16(f);
  u16 r; memcpy(&r, &h, 2); return r;
}
__device__ __forceinline__ float bf2f(u16 v) {
  u32 x = ((u32)v) << 16; float f; memcpy(&f, &x, 4); return f;
}

// async global->LDS, 16B per lane. LDS dest = (wave-uniform base) + lane*16.
__device__ __forceinline__ void glds16(const short* g, short* l) {
  __builtin_amdgcn_global_load_lds(
      (const __attribute__((address_space(1))) unsigned int*)(g),
      (__attribute__((address_space(3))) unsigned int*)(l), 16, 0, 0);
}

// ---------------- f32 -> bf16, vectorized ----------------
__global__ void k_f32_to_bf16v(const float4* __restrict__ src, ushort4* __restrict__ dst, int n4) {
  int i = blockIdx.x * blockDim.x + threadIdx.x;
  if (i < n4) {
    float4 v = src[i];
    ushort4 o; o.x = f2bf(v.x); o.y = f2bf(v.y); o.z = f2bf(v.z); o.w = f2bf(v.w);
    dst[i] = o;
  }
}

// ------- transpose+convert (+optional LN-fold): src [z][R,C] f32 -> dst [z][C,R] bf16
template<bool FOLD>
__global__ void k_transpose_fold(const float* __restrict__ src, bf16* __restrict__ dst,
                                 int R, int C, size_t sstride, size_t dstride,
                                 const float* __restrict__ gv, const float* __restrict__ bv,
                                 float* __restrict__ wacc, float* __restrict__ bacc,
                                 int vstride) {
  __shared__ float tile[32][33];
  int z = blockIdx.z;
  const float* s = src + (size_t)z * sstride;
  bf16* d = dst + (size_t)z * dstride;
  int r0 = blockIdx.y * 32, c0 = blockIdx.x * 32;
  int tx = threadIdx.x, ty = threadIdx.y;
#pragma unroll
  for (int i = ty; i < 32; i += 8)
    tile[i][tx] = s[(size_t)(r0 + i) * C + (c0 + tx)];
  __syncthreads();
  float gk = 1.0f;
  if (FOLD) gk = gv[(size_t)z * R + r0 + tx];
#pragma unroll
  for (int i = ty; i < 32; i += 8) {
    float val = tile[tx][i];
    if (FOLD) val *= gk;
    d[(size_t)(c0 + i) * R + (r0 + tx)] = __float2bfloat16(val);
  }
  if (FOLD && ty == 0) {
    const float* gz = gv + (size_t)z * R + r0;
    const float* bz = bv + (size_t)z * R + r0;
    float s1 = 0.f, s2 = 0.f;
#pragma unroll 8
    for (int j = 0; j < 32; j++) {
      float wv = tile[j][tx];
      s1 += gz[j] * wv;
      s2 += bz[j] * wv;
    }
    atomicAdd(&wacc[(size_t)z * vstride + c0 + tx], s1);
    atomicAdd(&bacc[(size_t)z * vstride + c0 + tx], s2);
  }
}

// ---------------- 256x256 8-wave 4-phase/K-step MFMA GEMM (counted-vmcnt pipeline) ----
// C[16384,N] = A[16384,K] * Bt[N,K]^T.  BM=BN=256, BK=64, 512 thr (2x4 waves).
// LDS: A/B each [2 buf][2 khalf][256 rows][32 k] bf16 (128 KiB total), XOR-swizzled
// (koct ^= (row>>1)&3) so both glds staging (linear dest, pre-swizzled source) and
// ds_read_b128 fragment reads are bank-conflict-free.
// Schedule per K-step t (4 phases, 16 MFMA each, 2 barriers/phase, setprio around MFMA):
//   ph0: stage A[kk1] of t+1 -> nxt ; read A kk0 rf0-3 + B kk0 cf0-3 ; MFMA rf0-3,kk0
//   ph1: stage B[kk0] of t+2 -> cur ; read A kk0 rf4-7              ; MFMA rf4-7,kk0
//   ph2: stage A[kk0] of t+2 -> cur ; read A kk1 rf0-3 + B kk1     ; MFMA rf0-3,kk1
//   ph3: stage B[kk1] of t+2 -> cur ; read A kk1 rf4-7              ; MFMA rf4-7,kk1
//        then s_waitcnt vmcnt(6) (3 regions in flight, never 0 mid-loop) ; barrier.
// The barrier after the vmcnt publishes cross-wave DMA completion (regions are staged
// cooperatively by all 8 waves; per-wave vmcnt alone is insufficient).
// MODE: 0 bias; 2 silu; 3 bias+residual(bf16,in-place); 4 split u|gate. LNFOLD/STATS as before.
template<int MODE, bool LNFOLD, bool STATS>
__global__ __launch_bounds__(512, 2) void k_gemm256(
    const short* __restrict__ A, const short* __restrict__ Bt,
    const float* __restrict__ bias, const float* __restrict__ bias2,
    const float* __restrict__ wvec, const float* __restrict__ bvec,
    const float* __restrict__ stats_in, float* __restrict__ stats_out,
    u16* __restrict__ res, u16* __restrict__ outp, u16* __restrict__ outp2,
    int N, int K, int ncol)
{
  __shared__ short As[4 * 8192];   // [buf*2+kk][8192 shorts = 256 rows x 32 k]
  __shared__ short Bs[4 * 8192];
  __shared__ float s_mu[256], s_rv[256];

  const int tid = threadIdx.x;
  const int lane = tid & 63, w = tid >> 6;
  const int wr = w >> 2, wc = w & 3;        // 2 x 4 wave grid, per-wave 128x64 output
  const int l16 = lane & 15, qd = lane >> 4;

  const int b = blockIdx.x;
  const int xcd = b & 7, tt = b >> 3;
  const int m0 = (xcd * 8 + tt / ncol) * 256;
  const int n0 = (tt % ncol) * 256;

  // ---- staging geometry: lane covers logical (row, koct); dest is linear lane*16 ----
  const int srow  = w * 16 + (lane >> 2);            // rows 0..127 (j=0) / +128 (j=1)
  const int skoct = (lane & 3) ^ ((lane >> 3) & 3);  // pre-swizzled source k-octet
  const short* pA0 = A  + (size_t)(m0 + srow) * K + skoct * 8;
  const short* pA1 = pA0 + (size_t)128 * K;
  const short* pB0 = Bt + (size_t)(n0 + srow) * K + skoct * 8;
  const short* pB1 = pB0 + (size_t)128 * K;

  auto stg = [&](short* region, const short* p0, const short* p1, int koff) {
    glds16(p0 + koff, region + w * 512);          // rows 0..127 of region
    glds16(p1 + koff, region + 4096 + w * 512);   // rows 128..255
  };

  // ---- fragment-read geometry (swizzled): phys = row*64 + ((koct ^ ((row>>1)&3))<<4) ----
  const int kx   = (qd ^ ((l16 >> 1) & 3)) << 4;
  const int aoff = (wr * 128 + l16) * 64 + kx;    // + rf*1024 per 16-row fragment
  const int boff = (wc * 64  + l16) * 64 + kx;    // + cf*1024 per 16-col fragment

  // LN stats load issued first so its waitcnt doesn't drain the staging queue
  float sv = 0.f, sq = 0.f;
  if (LNFOLD && tid < 256) {
    sv = stats_in[2 * (m0 + tid)];
    sq = stats_in[2 * (m0 + tid) + 1];
  }

  const int NT = K >> 6;
  // prologue: step0 {Bkk0, Akk0, Bkk1, Akk1}, step1 {Bkk0, Akk0, Bkk1} = 14 glds
  stg(Bs + 0 * 8192, pB0, pB1, 0);
  stg(As + 0 * 8192, pA0, pA1, 0);
  stg(Bs + 1 * 8192, pB0, pB1, 32);
  stg(As + 1 * 8192, pA0, pA1, 32);
  stg(Bs + 2 * 8192, pB0, pB1, 64);
  stg(As + 2 * 8192, pA0, pA1, 64);
  stg(Bs + 3 * 8192, pB0, pB1, 96);

  if (LNFOLD && tid < 256) {
    float mu  = sv * (1.0f / (float)D_MOD);
    float var = sq * (1.0f / (float)D_MOD) - mu * mu;
    s_mu[tid] = mu;
    s_rv[tid] = 1.0f / sqrtf(var + EPSV);
  }

  f32x4 acc[8][4];
#pragma unroll
  for (int i = 0; i < 8; i++)
#pragma unroll
    for (int j = 0; j < 4; j++) acc[i][j] = (f32x4){0.f, 0.f, 0.f, 0.f};

  // wait for step 0's 4 regions (leave step-1's 3 regions in flight), publish to all waves
  asm volatile("s_waitcnt vmcnt(6)" ::: "memory");
  __builtin_amdgcn_s_barrier();

  bf16x8 af[4], b0f[4], b1f[4];
  int buf = 0;
  for (int t = 0; t < NT; ++t, buf ^= 1) {
    const char* Ak0 = (const char*)As + buf * 32768;
    const char* Ak1 = Ak0 + 16384;
    const char* Bk0 = (const char*)Bs + buf * 32768;
    const char* Bk1 = Bk0 + 16384;
    const int nb = buf ^ 1;

    // ---- phase 0 ----
    if (t + 1 < NT) stg(As + (nb * 2 + 1) * 8192, pA0, pA1, (t + 1) * 64 + 32);
#pragma unroll
    for (int i = 0; i < 4; i++) af[i]  = *(const bf16x8*)(Ak0 + aoff + i * 1024);
#pragma unroll
    for (int i = 0; i < 4; i++) b0f[i] = *(const bf16x8*)(Bk0 + boff + i * 1024);
    __builtin_amdgcn_s_barrier();
    __builtin_amdgcn_s_setprio(1);
#pragma unroll
    for (int rf = 0; rf < 4; rf++)
#pragma unroll
      for (int cf = 0; cf < 4; cf++)
        acc[rf][cf] = __builtin_amdgcn_mfma_f32_16x16x32_bf16(af[rf], b0f[cf], acc[rf][cf], 0, 0, 0);
    __builtin_amdgcn_s_setprio(0);
    __builtin_amdgcn_s_barrier();

    // ---- phase 1 ----
    if (t + 2 < NT) stg(Bs + (buf * 2 + 0) * 8192, pB0, pB1, (t + 2) * 64);
#pragma unroll
    for (int i = 0; i < 4; i++) af[i] = *(const bf16x8*)(Ak0 + aoff + (4 + i) * 1024);
    __builtin_amdgcn_s_barrier();
    __builtin_amdgcn_s_setprio(1);
#pragma unroll
    for (int rf = 0; rf < 4; rf++)
#pragma unroll
      for (int cf = 0; cf < 4; cf++)
        acc[4 + rf][cf] = __builtin_amdgcn_mfma_f32_16x16x32_bf16(af[rf], b0f[cf], acc[4 + rf][cf], 0, 0, 0);
    __builtin_amdgcn_s_setprio(0);
    __builtin_amdgcn_s_barrier();

    // ---- phase 2 ----
    if (t + 2 < NT) stg(As + (buf * 2 + 0) * 8192, pA0, pA1, (t + 2) * 64);
#pragma unroll
    for (int i = 0; i < 4; i++) af[i]  = *(const bf16x8*)(Ak1 + aoff + i * 1024);
#pragma unroll
    for (int i = 0; i < 4; i++) b1f[i] = *(const bf16x8*)(Bk1 + boff + i * 1024);
    __builtin_amdgcn_s_barrier();
    __builtin_amdgcn_s_setprio(1);
#pragma unroll
    for (int rf = 0; rf < 4; rf++)
#pragma unroll
      for (int cf = 0; cf < 4; cf++)
        acc[rf][cf] = __builtin_amdgcn_mfma_f32_16x16x32_bf16(af[rf], b1f[cf], acc[rf][cf], 0, 0, 0);
    __builtin_amdgcn_s_setprio(0);
    __builtin_amdgcn_s_barrier();

    // ---- phase 3 ----
    if (t + 2 < NT) stg(Bs + (buf * 2 + 1) * 8192, pB0, pB1, (t + 2) * 64 + 32);
#pragma unroll
    for (int i = 0; i < 4; i++) af[i] = *(const bf16x8*)(Ak1 + aoff + (4 + i) * 1024);
    __builtin_amdgcn_s_barrier();
    __builtin_amdgcn_s_setprio(1);
#pragma unroll
    for (int rf = 0; rf < 4; rf++)
#pragma unroll
      for (int cf = 0; cf < 4; cf++)
        acc[4 + rf][cf] = __builtin_amdgcn_mfma_f32_16x16x32_bf16(af[rf], b1f[cf], acc[4 + rf][cf], 0, 0, 0);
    __builtin_amdgcn_s_setprio(0);
    // next step's youngest region (A[kk1] of t+1) must land; keep 3 regions in flight
    if (t + 2 < NT) asm volatile("s_waitcnt vmcnt(6)" ::: "memory");
    else            asm volatile("s_waitcnt vmcnt(0)" ::: "memory");
    __builtin_amdgcn_s_barrier();
  }

  // ---- epilogue. C/D map col=lane&15, row=(lane>>4)*4+reg ----
  const float* bb = bias;
  u16* op = outp;
  int nofs = 0, Nout = N;
  bool sig = false;
  if (MODE == 4) {
    Nout = N >> 1;
    if (n0 >= Nout) { bb = bias2; op = outp2; nofs = Nout; sig = true; }
  }
  const int gmb = m0 + wr * 128 + qd * 4;
  const int gnb = n0 + wc * 64 + l16;
  float bc[4], wv4[4], bv4[4];
#pragma unroll
  for (int cf = 0; cf < 4; cf++) {
    int gn = gnb + cf * 16;
    bc[cf] = bb[gn - nofs];
    if (LNFOLD) { wv4[cf] = wvec[gn]; bv4[cf] = bvec[gn]; }
  }
#pragma unroll
  for (int rf = 0; rf < 8; rf++) {
#pragma unroll
    for (int r = 0; r < 4; r++) {
      const int gm = gmb + rf * 16 + r;
      float mu = 0.f, rv = 0.f;
      if (LNFOLD) { mu = s_mu[gm - m0]; rv = s_rv[gm - m0]; }
      float ps = 0.f, ps2 = 0.f;
#pragma unroll
      for (int cf = 0; cf < 4; cf++) {
        int gn = gnb + cf * 16;
        float vv = acc[rf][cf][r];
        if (LNFOLD) vv = rv * vv - rv * mu * wv4[cf] + bv4[cf] + bc[cf];
        else        vv += bc[cf];
        if (MODE == 2) vv = vv * fsigmoid(vv);
        if (MODE == 4 && sig) vv = fsigmoid(vv);
        size_t oidx = (size_t)gm * Nout + (gn - nofs);
        if (MODE == 3) vv += bf2f(res[oidx]);
        u16 rb = f2bf(vv);
        op[oidx] = rb;
        if (STATS) { float fv = bf2f(rb); ps += fv; ps2 += fv * fv; }
      }
      if (STATS) {
#pragma unroll
        for (int o = 1; o < 16; o <<= 1) {
          ps  += __shfl_xor(ps, o, 64);
          ps2 += __shfl_xor(ps2, o, 64);
        }
        if (l16 == 0) {
          atomicAdd(&stats_out[2 * gm], ps);
          atomicAdd(&stats_out[2 * gm + 1], ps2);
        }
      }
    }
  }
}

// ---------------- chunked linear-recurrence scan (u bf16, 4 ch/thread) ----------------
__global__ void k_scan_a(const bf16* __restrict__ u, const float* __restrict__ dl,
                         float* __restrict__ clast) {
  int t = threadIdx.x;            // 0..191
  int g = blockIdx.x;
  int d0 = t * 4;
  float dec[4], s[4] = {0.f, 0.f, 0.f, 0.f};
#pragma unroll
  for (int c = 0; c < 4; c++) dec[c] = fsigmoid(dl[d0 + c]);
  const ushort4* up = (const ushort4*)(u + (size_t)g * S_T * D_MOD) + t;
  for (int tt = 0; tt < S_T; tt++) {
    ushort4 uv = up[(size_t)tt * 192];
    s[0] = fmaf(dec[0], s[0], bf2f(uv.x));
    s[1] = fmaf(dec[1], s[1], bf2f(uv.y));
    s[2] = fmaf(dec[2], s[2], bf2f(uv.z));
    s[3] = fmaf(dec[3], s[3], bf2f(uv.w));
  }
#pragma unroll
  for (int c = 0; c < 4; c++) clast[(size_t)g * D_MOD + d0 + c] = s[c];
}

__global__ void k_scan_b(const float* __restrict__ clast, const float* __restrict__ dl,
                         float* __restrict__ carry) {
  int d = threadIdx.x;
  float decay = fsigmoid(dl[d]);
  float aT = decay;
#pragma unroll
  for (int i = 0; i < 6; i++) aT *= aT;   // decay^64
  float c = 0.f;
  for (int g = 0; g < S_G; g++) {
    carry[(size_t)g * D_MOD + d] = c;
    c = fmaf(aT, c, clast[(size_t)g * D_MOD + d]);
  }
}

__global__ void k_scan_c(const bf16* __restrict__ u, const float* __restrict__ dl,
                         const float* __restrict__ carry, bf16* __restrict__ gate_s) {
  int t = threadIdx.x;            // 0..191
  int g = blockIdx.x;
  int d0 = t * 4;
  float dec[4], s[4];
#pragma unroll
  for (int c = 0; c < 4; c++) {
    dec[c] = fsigmoid(dl[d0 + c]);
    s[c] = carry[(size_t)g * D_MOD + d0 + c];
  }
  const ushort4* up = (const ushort4*)(u + (size_t)g * S_T * D_MOD) + t;
  ushort4* gp = (ushort4*)(gate_s + (size_t)g * S_T * D_MOD) + t;
  for (int tt = 0; tt < S_T; tt++) {
    ushort4 uv = up[(size_t)tt * 192];
    ushort4 gv = gp[(size_t)tt * 192];
    s[0] = fmaf(dec[0], s[0], bf2f(uv.x));
    s[1] = fmaf(dec[1], s[1], bf2f(uv.y));
    s[2] = fmaf(dec[2], s[2], bf2f(uv.z));
    s[3] = fmaf(dec[3], s[3], bf2f(uv.w));
    ushort4 ov;
    ov.x = f2bf(s[0] * bf2f(gv.x));
    ov.y = f2bf(s[1] * bf2f(gv.y));
    ov.z = f2bf(s[2] * bf2f(gv.z));
    ov.w = f2bf(s[3] * bf2f(gv.w));
    gp[(size_t)tt * 192] = ov;
  }
}

// ---------------- final LN: x bf16 + precomputed stats -> f32 out ----------------
__global__ __launch_bounds__(256) void k_ln_final(const u16* __restrict__ x,
    const float* __restrict__ stats, const float* __restrict__ g,
    const float* __restrict__ b, float* __restrict__ outp) {
  int wv = threadIdx.x >> 6, lane = threadIdx.x & 63;
  int row = blockIdx.x * 4 + wv;
  float sv = stats[2 * row], sq = stats[2 * row + 1];
  float mu = sv * (1.0f / (float)D_MOD);
  float var = sq * (1.0f / (float)D_MOD) - mu * mu;
  float rv = 1.0f / sqrtf(var + EPSV);
  const ushort4* xr = (const ushort4*)(x + (size_t)row * D_MOD);
  const float4* g4 = (const float4*)g;
  const float4* b4 = (const float4*)b;
  float4* o4 = (float4*)(outp + (size_t)row * D_MOD);
#pragma unroll
  for (int j = 0; j < 3; j++) {
    int f = j * 64 + lane;
    ushort4 xv = xr[f];
    float4 gg = g4[f], bb = b4[f], ov;
    ov.x = (bf2f(xv.x) - mu) * rv * gg.x + bb.x;
    ov.y = (bf2f(xv.y) - mu) * rv * gg.y + bb.y;
    ov.z = (bf2f(xv.z) - mu) * rv * gg.z + bb.z;
    ov.w = (bf2f(xv.w) - mu) * rv * gg.w + bb.w;
    o4[f] = ov;
  }
}

extern "C" void kernel_launch(void* const* d_in, const int* in_sizes, int n_in,
                              void* d_out, int out_size, void* d_ws, size_t ws_size,
                              hipStream_t stream) {
  const float* nf     = (const float*)d_in[0];
  const float* W_proj = (const float*)d_in[1];
  const float* b_proj = (const float*)d_in[2];
  const float* ln_s_g = (const float*)d_in[3];
  const float* ln_s_b = (const float*)d_in[4];
  const float* W_in   = (const float*)d_in[5];
  const float* b_in   = (const float*)d_in[6];
  const float* W_gate = (const float*)d_in[7];
  const float* b_gate = (const float*)d_in[8];
  const float* W_out  = (const float*)d_in[9];
  const float* b_out  = (const float*)d_in[10];
  const float* dlogit = (const float*)d_in[11];
  const float* ln_f_g = (const float*)d_in[12];
  const float* ln_f_b = (const float*)d_in[13];
  const float* W_ff1  = (const float*)d_in[14];
  const float* b_ff1  = (const float*)d_in[15];
  const float* W_ff2  = (const float*)d_in[16];
  const float* b_ff2  = (const float*)d_in[17];
  const float* ln_o_g = (const float*)d_in[18];
  const float* ln_o_b = (const float*)d_in[19];
  (void)in_sizes; (void)n_in;

  char* ws = (char*)d_ws;
  size_t off = 0;
  auto alloc = [&](size_t bytes) -> char* {
    char* p = ws + off;
    off = (off + bytes + 255) & ~(size_t)255;
    return p;
  };
  const bool big = ws_size >= (160ull << 20);
  const size_t wmul = big ? N_LAYER : 1;

  u16*   x     = (u16*)alloc(2ull * L_TOK * D_MOD);        // residual stream, bf16 (25 MB)
  // shared region (50.3 MB): nfb (pre-loop) | u+gate (recurrence) | tb (FF)
  char*  ug    = alloc(2ull * L_TOK * D_FF);
  u16*   u     = (u16*)ug;
  u16*   gate  = (u16*)(ug + 2ull * L_TOK * D_MOD);
  u16*   tb    = (u16*)ug;
  u16*   nfb   = (u16*)ug;
  bf16*  WprojT= (bf16*)alloc(2ull * D_INP * D_MOD);
  bf16*  WigT  = (bf16*)alloc(2ull * wmul * (2 * D_MOD) * D_MOD);  // [g∘W_in^T ; g∘W_gate^T]
  bf16*  WoT   = (bf16*)alloc(2ull * wmul * D_MOD * D_MOD);
  bf16*  Wff1T = (bf16*)alloc(2ull * wmul * D_MOD * D_FF);
  bf16*  Wff2T = (bf16*)alloc(2ull * wmul * D_FF * D_MOD);
  float* clast = (float*)alloc(sizeof(float) * (size_t)S_G * D_MOD);
  float* carry = (float*)alloc(sizeof(float) * (size_t)S_G * D_MOD);
  // zeroed region: stats slots [17][16384][2] + fold vectors
  char*  zbase = alloc(0);
  float* stats = (float*)alloc(sizeof(float) * 17ull * L_TOK * 2);     // 2.23 MB
  float* wvig  = (float*)alloc(sizeof(float) * N_LAYER * 2 * D_MOD);   // g_s@[W_in|W_gate]
  float* bvig  = (float*)alloc(sizeof(float) * N_LAYER * 2 * D_MOD);
  float* wvf1  = (float*)alloc(sizeof(float) * N_LAYER * D_FF);        // g_f@W_ff1
  float* bvf1  = (float*)alloc(sizeof(float) * N_LAYER * D_FF);
  size_t zbytes = (size_t)((char*)ws + off - zbase);
  hipMemsetAsync(zbase, 0, zbytes, stream);

  const size_t DD = (size_t)D_MOD * D_MOD, DF = (size_t)D_MOD * D_FF;
  auto statslot = [&](int s) { return stats + (size_t)s * L_TOK * 2; };
  dim3 tb32(32, 8);
  k_f32_to_bf16v<<<(L_TOK * D_INP / 4 + 255) / 256, 256, 0, stream>>>(
      (const float4*)nf, (ushort4*)nfb, L_TOK * D_INP / 4);
  k_transpose_fold<false><<<dim3(D_MOD / 32, D_INP / 32, 1), tb32, 0, stream>>>(
      W_proj, WprojT, D_INP, D_MOD, 0, 0, nullptr, nullptr, nullptr, nullptr, 0);
  if (big) {
    k_transpose_fold<true><<<dim3(D_MOD / 32, D_MOD / 32, N_LAYER), tb32, 0, stream>>>(
        W_in,   WigT,      D_MOD, D_MOD, DD, 2 * DD, ln_s_g, ln_s_b, wvig,       bvig,       2 * D_MOD);
    k_transpose_fold<true><<<dim3(D_MOD / 32, D_MOD / 32, N_LAYER), tb32, 0, stream>>>(
        W_gate, WigT + DD, D_MOD, D_MOD, DD, 2 * DD, ln_s_g, ln_s_b, wvig + D_MOD, bvig + D_MOD, 2 * D_MOD);
    k_transpose_fold<false><<<dim3(D_MOD / 32, D_MOD / 32, N_LAYER), tb32, 0, stream>>>(
        W_out,  WoT,       D_MOD, D_MOD, DD, DD, nullptr, nullptr, nullptr, nullptr, 0);
    k_transpose_fold<true><<<dim3(D_FF / 32,  D_MOD / 32, N_LAYER), tb32, 0, stream>>>(
        W_ff1,  Wff1T,     D_MOD, D_FF,  DF, DF, ln_f_g, ln_f_b, wvf1, bvf1, D_FF);
    k_transpose_fold<false><<<dim3(D_MOD / 32, D_FF / 32,  N_LAYER), tb32, 0, stream>>>(
        W_ff2,  Wff2T,     D_FF,  D_MOD, DF, DF, nullptr, nullptr, nullptr, nullptr, 0);
  }

  // x = nf @ W_proj + b_proj  (bf16 out + stats slot 0)
  k_gemm256<0, false, true><<<64 * 3, 512, 0, stream>>>(
      (const short*)nfb, (const short*)WprojT, b_proj, nullptr, nullptr, nullptr,
      nullptr, statslot(0), nullptr, x, nullptr, D_MOD, D_INP, 3);

  for (int l = 0; l < N_LAYER; l++) {
    const bf16 *wigT, *woT, *wf1T, *wf2T;
    if (big) {
      wigT = WigT  + (size_t)l * 2 * DD;
      woT  = WoT   + (size_t)l * DD;
      wf1T = Wff1T + (size_t)l * DF;
      wf2T = Wff2T + (size_t)l * DF;
    } else {
      k_transpose_fold<true><<<dim3(D_MOD / 32, D_MOD / 32, 1), tb32, 0, stream>>>(
          W_in + (size_t)l * DD, WigT, D_MOD, D_MOD, 0, 0,
          ln_s_g + l * D_MOD, ln_s_b + l * D_MOD, wvig + (size_t)l * 2 * D_MOD, bvig + (size_t)l * 2 * D_MOD, 0);
      k_transpose_fold<true><<<dim3(D_MOD / 32, D_MOD / 32, 1), tb32, 0, stream>>>(
          W_gate + (size_t)l * DD, WigT + DD, D_MOD, D_MOD, 0, 0,
          ln_s_g + l * D_MOD, ln_s_b + l * D_MOD, wvig + (size_t)l * 2 * D_MOD + D_MOD, bvig + (size_t)l * 2 * D_MOD + D_MOD, 0);
      k_transpose_fold<false><<<dim3(D_MOD / 32, D_MOD / 32, 1), tb32, 0, stream>>>(
          W_out + (size_t)l * DD, WoT, D_MOD, D_MOD, 0, 0, nullptr, nullptr, nullptr, nullptr, 0);
      k_transpose_fold<true><<<dim3(D_FF / 32, D_MOD / 32, 1), tb32, 0, stream>>>(
          W_ff1 + (size_t)l * DF, Wff1T, D_MOD, D_FF, 0, 0,
          ln_f_g + l * D_MOD, ln_f_b + l * D_MOD, wvf1 + (size_t)l * D_FF, bvf1 + (size_t)l * D_FF, 0);
      k_transpose_fold<false><<<dim3(D_MOD / 32, D_FF / 32, 1), tb32, 0, stream>>>(
          W_ff2 + (size_t)l * DF, Wff2T, D_FF, D_MOD, 0, 0, nullptr, nullptr, nullptr, nullptr, 0);
      wigT = WigT; woT = WoT; wf1T = Wff1T; wf2T = Wff2T;
    }

    // fused LN_s + (u | gate) GEMM: A = x directly
    k_gemm256<4, true, false><<<64 * 6, 512, 0, stream>>>(
        (const short*)x, (const short*)wigT, b_in + l * D_MOD, b_gate + l * D_MOD,
        wvig + (size_t)l * 2 * D_MOD, bvig + (size_t)l * 2 * D_MOD,
        statslot(2 * l), nullptr, nullptr, u, gate, 2 * D_MOD, D_MOD, 6);
    // chunked scan; s*gate -> gate buffer (bf16)
    k_scan_a<<<S_G, 192, 0, stream>>>((const bf16*)u, dlogit + l * D_MOD, clast);
    k_scan_b<<<1, D_MOD, 0, stream>>>(clast, dlogit + l * D_MOD, carry);
    k_scan_c<<<S_G, 192, 0, stream>>>((const bf16*)u, dlogit + l * D_MOD, carry, (bf16*)gate);
    // x = x + sg @ W_out + b_out  (bf16 in-place + stats slot 2l+1)
    k_gemm256<3, false, true><<<64 * 3, 512, 0, stream>>>(
        (const short*)gate, (const short*)woT, b_out + l * D_MOD, nullptr, nullptr, nullptr,
        nullptr, statslot(2 * l + 1), x, x, nullptr, D_MOD, D_MOD, 3);
    // fused LN_f + FF1 (silu): A = x directly
    k_gemm256<2, true, false><<<64 * 6, 512, 0, stream>>>(
        (const short*)x, (const short*)wf1T, b_ff1 + l * D_FF, nullptr,
        wvf1 + (size_t)l * D_FF, bvf1 + (size_t)l * D_FF,
        statslot(2 * l + 1), nullptr, nullptr, tb, nullptr, D_FF, D_MOD, 6);
    // x = x + tb @ W_ff2 + b_ff2  (bf16 in-place + stats slot 2l+2)
    k_gemm256<3, false, true><<<64 * 3, 512, 0, stream>>>(
        (const short*)tb, (const short*)wf2T, b_ff2 + l * D_MOD, nullptr, nullptr, nullptr,
        nullptr, statslot(2 * l + 2), x, x, nullptr, D_MOD, D_FF, 3);
  }

  // out = LN_o(x) (f32) using stats slot 16
  k_ln_final<<<L_TOK / 4, 256, 0, stream>>>(x, statslot(2 * N_LAYER), ln_o_g, ln_o_b, (float*)d_out);
}

// Round 4
// 2499.784 us; speedup vs baseline: 1.0394x; 1.0394x over previous
//
#include <hip/hip_runtime.h>
#include <hip/hip_bf16.h>
#include <math.h>
#include <string.h>

#define L_TOK 16384
#define D_INP 256
#define D_MOD 768
#define D_FF  1536
#define N_LAYER 8
#define S_T 64
#define S_G 256
#define EPSV 1e-5f

typedef short bf16x8 __attribute__((ext_vector_type(8)));
typedef float f32x4 __attribute__((ext_vector_type(4)));
typedef __hip_bfloat16 bf16;
typedef unsigned int u32;
typedef unsigned short u16;

__device__ __forceinline__ float fsigmoid(float z) { return 1.0f / (1.0f + __expf(-z)); }

__device__ __forceinline__ u16 f2bf(float f) {
  __hip_bfloat16 h = __float2bfloat16(f);
  u16 r; memcpy(&r, &h, 2); return r;
}
__device__ __forceinline__ float bf2f(u16 v) {
  u32 x = ((u32)v) << 16; float f; memcpy(&f, &x, 4); return f;
}

// async global->LDS, 16B per lane. LDS dest = (wave-uniform base) + lane*16.
__device__ __forceinline__ void glds16(const short* g, short* l) {
  __builtin_amdgcn_global_load_lds(
      (const __attribute__((address_space(1))) unsigned int*)(g),
      (__attribute__((address_space(3))) unsigned int*)(l), 16, 0, 0);
}

// inline-asm ds_read_b128: OPAQUE to the compiler's waitcnt pass, so it cannot
// insert a conservative vmcnt(0) drain against outstanding global_load_lds ops
// (that drain collapsed the round-3 pipeline: every phase waited for the t+2
// prefetch just issued). We control completion with explicit s_waitcnt
// lgkmcnt(0) + sched_barrier(0) (rule 18) before each MFMA cluster.
__device__ __forceinline__ bf16x8 dsr128(const char* base, int imm) {
  bf16x8 r;
  const __attribute__((address_space(3))) char* p =
      (const __attribute__((address_space(3))) char*)base;
  asm volatile("ds_read_b128 %0, %1 offset:%c2" : "=v"(r) : "v"(p), "i"(imm));
  return r;
}

// ---------------- f32 -> bf16, vectorized ----------------
__global__ void k_f32_to_bf16v(const float4* __restrict__ src, ushort4* __restrict__ dst, int n4) {
  int i = blockIdx.x * blockDim.x + threadIdx.x;
  if (i < n4) {
    float4 v = src[i];
    ushort4 o; o.x = f2bf(v.x); o.y = f2bf(v.y); o.z = f2bf(v.z); o.w = f2bf(v.w);
    dst[i] = o;
  }
}

// ------- transpose+convert (+optional LN-fold): src [z][R,C] f32 -> dst [z][C,R] bf16
template<bool FOLD>
__global__ void k_transpose_fold(const float* __restrict__ src, bf16* __restrict__ dst,
                                 int R, int C, size_t sstride, size_t dstride,
                                 const float* __restrict__ gv, const float* __restrict__ bv,
                                 float* __restrict__ wacc, float* __restrict__ bacc,
                                 int vstride) {
  __shared__ float tile[32][33];
  int z = blockIdx.z;
  const float* s = src + (size_t)z * sstride;
  bf16* d = dst + (size_t)z * dstride;
  int r0 = blockIdx.y * 32, c0 = blockIdx.x * 32;
  int tx = threadIdx.x, ty = threadIdx.y;
#pragma unroll
  for (int i = ty; i < 32; i += 8)
    tile[i][tx] = s[(size_t)(r0 + i) * C + (c0 + tx)];
  __syncthreads();
  float gk = 1.0f;
  if (FOLD) gk = gv[(size_t)z * R + r0 + tx];
#pragma unroll
  for (int i = ty; i < 32; i += 8) {
    float val = tile[tx][i];
    if (FOLD) val *= gk;
    d[(size_t)(c0 + i) * R + (r0 + tx)] = __float2bfloat16(val);
  }
  if (FOLD && ty == 0) {
    const float* gz = gv + (size_t)z * R + r0;
    const float* bz = bv + (size_t)z * R + r0;
    float s1 = 0.f, s2 = 0.f;
#pragma unroll 8
    for (int j = 0; j < 32; j++) {
      float wv = tile[j][tx];
      s1 += gz[j] * wv;
      s2 += bz[j] * wv;
    }
    atomicAdd(&wacc[(size_t)z * vstride + c0 + tx], s1);
    atomicAdd(&bacc[(size_t)z * vstride + c0 + tx], s2);
  }
}

// ---------------- 256x256 8-wave 4-phase/K-step MFMA GEMM (counted-vmcnt pipeline) ----
// Same schedule as round 3, with the fragment reads now inline-asm (see dsr128).
// Per phase: {stage glds ; asm ds_read frags ; barrier ; lgkmcnt(0)+sched_barrier(0) ;
//             setprio(1) 16 MFMA setprio(0) ; barrier}.
// End of K-step: s_waitcnt vmcnt(6) (3 regions = 6 glds stay in flight), barrier.
// Staging safety: each phase's lgkmcnt(0) asm carries a "memory" clobber, so glds16
// issues cannot hoist above the reads of the region they overwrite; trailing barriers
// make the t+2-into-cur staging safe exactly as in round 3.
template<int MODE, bool LNFOLD, bool STATS>
__global__ __launch_bounds__(512, 2) void k_gemm256(
    const short* __restrict__ A, const short* __restrict__ Bt,
    const float* __restrict__ bias, const float* __restrict__ bias2,
    const float* __restrict__ wvec, const float* __restrict__ bvec,
    const float* __restrict__ stats_in, float* __restrict__ stats_out,
    u16* __restrict__ res, u16* __restrict__ outp, u16* __restrict__ outp2,
    int N, int K, int ncol)
{
  __shared__ short As[4 * 8192];   // [buf*2+kk][8192 shorts = 256 rows x 32 k]
  __shared__ short Bs[4 * 8192];
  __shared__ float s_mu[256], s_rv[256];

  const int tid = threadIdx.x;
  const int lane = tid & 63, w = tid >> 6;
  const int wr = w >> 2, wc = w & 3;        // 2 x 4 wave grid, per-wave 128x64 output
  const int l16 = lane & 15, qd = lane >> 4;

  const int b = blockIdx.x;
  const int xcd = b & 7, tt = b >> 3;
  const int m0 = (xcd * 8 + tt / ncol) * 256;
  const int n0 = (tt % ncol) * 256;

  // ---- staging geometry: lane covers logical (row, koct); dest is linear lane*16 ----
  const int srow  = w * 16 + (lane >> 2);            // rows 0..127 (j=0) / +128 (j=1)
  const int skoct = (lane & 3) ^ ((lane >> 3) & 3);  // pre-swizzled source k-octet
  const short* pA0 = A  + (size_t)(m0 + srow) * K + skoct * 8;
  const short* pA1 = pA0 + (size_t)128 * K;
  const short* pB0 = Bt + (size_t)(n0 + srow) * K + skoct * 8;
  const short* pB1 = pB0 + (size_t)128 * K;

  auto stg = [&](short* region, const short* p0, const short* p1, int koff) {
    glds16(p0 + koff, region + w * 512);          // rows 0..127 of region
    glds16(p1 + koff, region + 4096 + w * 512);   // rows 128..255
  };

  // ---- fragment-read geometry (swizzled): phys = row*64B + ((koct ^ ((row>>1)&3))*16B)
  const int kx   = (qd ^ ((l16 >> 1) & 3)) << 4;
  const int aoff = (wr * 128 + l16) * 64 + kx;    // + rf*1024 per 16-row fragment
  const int boff = (wc * 64  + l16) * 64 + kx;    // + cf*1024 per 16-col fragment

  // LN stats load issued first so its waitcnt doesn't drain the staging queue
  float sv = 0.f, sq = 0.f;
  if (LNFOLD && tid < 256) {
    sv = stats_in[2 * (m0 + tid)];
    sq = stats_in[2 * (m0 + tid) + 1];
  }

  const int NT = K >> 6;
  // prologue: step0 {Bkk0, Akk0, Bkk1, Akk1}, step1 {Bkk0, Akk0, Bkk1} = 14 glds
  stg(Bs + 0 * 8192, pB0, pB1, 0);
  stg(As + 0 * 8192, pA0, pA1, 0);
  stg(Bs + 1 * 8192, pB0, pB1, 32);
  stg(As + 1 * 8192, pA0, pA1, 32);
  stg(Bs + 2 * 8192, pB0, pB1, 64);
  stg(As + 2 * 8192, pA0, pA1, 64);
  stg(Bs + 3 * 8192, pB0, pB1, 96);

  if (LNFOLD && tid < 256) {
    float mu  = sv * (1.0f / (float)D_MOD);
    float var = sq * (1.0f / (float)D_MOD) - mu * mu;
    s_mu[tid] = mu;
    s_rv[tid] = 1.0f / sqrtf(var + EPSV);
  }

  f32x4 acc[8][4];
#pragma unroll
  for (int i = 0; i < 8; i++)
#pragma unroll
    for (int j = 0; j < 4; j++) acc[i][j] = (f32x4){0.f, 0.f, 0.f, 0.f};

  // wait for step 0's 4 regions (leave step-1's 3 regions in flight), publish to all waves
  asm volatile("s_waitcnt vmcnt(6)" ::: "memory");
  __builtin_amdgcn_s_barrier();

  bf16x8 af[4], b0f[4], b1f[4];
  int buf = 0;
  for (int t = 0; t < NT; ++t, buf ^= 1) {
    const char* Ak0 = (const char*)As + buf * 32768;
    const char* Ak1 = Ak0 + 16384;
    const char* Bk0 = (const char*)Bs + buf * 32768;
    const char* Bk1 = Bk0 + 16384;
    const int nb = buf ^ 1;
    const char* Ab0 = Ak0 + aoff;   // A fragment base, kk0
    const char* Ab1 = Ak1 + aoff;   // kk1
    const char* Bb0 = Bk0 + boff;
    const char* Bb1 = Bk1 + boff;

    // ---- phase 0: MFMA rf0-3 x kk0 ----
    if (t + 1 < NT) stg(As + (nb * 2 + 1) * 8192, pA0, pA1, (t + 1) * 64 + 32);
    af[0] = dsr128(Ab0, 0);    af[1] = dsr128(Ab0, 1024);
    af[2] = dsr128(Ab0, 2048); af[3] = dsr128(Ab0, 3072);
    b0f[0] = dsr128(Bb0, 0);    b0f[1] = dsr128(Bb0, 1024);
    b0f[2] = dsr128(Bb0, 2048); b0f[3] = dsr128(Bb0, 3072);
    __builtin_amdgcn_s_barrier();
    asm volatile("s_waitcnt lgkmcnt(0)" ::: "memory");
    __builtin_amdgcn_sched_barrier(0);
    __builtin_amdgcn_s_setprio(1);
#pragma unroll
    for (int rf = 0; rf < 4; rf++)
#pragma unroll
      for (int cf = 0; cf < 4; cf++)
        acc[rf][cf] = __builtin_amdgcn_mfma_f32_16x16x32_bf16(af[rf], b0f[cf], acc[rf][cf], 0, 0, 0);
    __builtin_amdgcn_s_setprio(0);
    __builtin_amdgcn_s_barrier();

    // ---- phase 1: MFMA rf4-7 x kk0 ----
    if (t + 2 < NT) stg(Bs + (buf * 2 + 0) * 8192, pB0, pB1, (t + 2) * 64);
    af[0] = dsr128(Ab0, 4096); af[1] = dsr128(Ab0, 5120);
    af[2] = dsr128(Ab0, 6144); af[3] = dsr128(Ab0, 7168);
    __builtin_amdgcn_s_barrier();
    asm volatile("s_waitcnt lgkmcnt(0)" ::: "memory");
    __builtin_amdgcn_sched_barrier(0);
    __builtin_amdgcn_s_setprio(1);
#pragma unroll
    for (int rf = 0; rf < 4; rf++)
#pragma unroll
      for (int cf = 0; cf < 4; cf++)
        acc[4 + rf][cf] = __builtin_amdgcn_mfma_f32_16x16x32_bf16(af[rf], b0f[cf], acc[4 + rf][cf], 0, 0, 0);
    __builtin_amdgcn_s_setprio(0);
    __builtin_amdgcn_s_barrier();

    // ---- phase 2: MFMA rf0-3 x kk1 ----
    if (t + 2 < NT) stg(As + (buf * 2 + 0) * 8192, pA0, pA1, (t + 2) * 64);
    af[0] = dsr128(Ab1, 0);    af[1] = dsr128(Ab1, 1024);
    af[2] = dsr128(Ab1, 2048); af[3] = dsr128(Ab1, 3072);
    b1f[0] = dsr128(Bb1, 0);    b1f[1] = dsr128(Bb1, 1024);
    b1f[2] = dsr128(Bb1, 2048); b1f[3] = dsr128(Bb1, 3072);
    __builtin_amdgcn_s_barrier();
    asm volatile("s_waitcnt lgkmcnt(0)" ::: "memory");
    __builtin_amdgcn_sched_barrier(0);
    __builtin_amdgcn_s_setprio(1);
#pragma unroll
    for (int rf = 0; rf < 4; rf++)
#pragma unroll
      for (int cf = 0; cf < 4; cf++)
        acc[rf][cf] = __builtin_amdgcn_mfma_f32_16x16x32_bf16(af[rf], b1f[cf], acc[rf][cf], 0, 0, 0);
    __builtin_amdgcn_s_setprio(0);
    __builtin_amdgcn_s_barrier();

    // ---- phase 3: MFMA rf4-7 x kk1 ----
    if (t + 2 < NT) stg(Bs + (buf * 2 + 1) * 8192, pB0, pB1, (t + 2) * 64 + 32);
    af[0] = dsr128(Ab1, 4096); af[1] = dsr128(Ab1, 5120);
    af[2] = dsr128(Ab1, 6144); af[3] = dsr128(Ab1, 7168);
    __builtin_amdgcn_s_barrier();
    asm volatile("s_waitcnt lgkmcnt(0)" ::: "memory");
    __builtin_amdgcn_sched_barrier(0);
    __builtin_amdgcn_s_setprio(1);
#pragma unroll
    for (int rf = 0; rf < 4; rf++)
#pragma unroll
      for (int cf = 0; cf < 4; cf++)
        acc[4 + rf][cf] = __builtin_amdgcn_mfma_f32_16x16x32_bf16(af[rf], b1f[cf], acc[4 + rf][cf], 0, 0, 0);
    __builtin_amdgcn_s_setprio(0);
    // next step's youngest region (A[kk1] of t+1) must land; keep 3 regions in flight
    if (t + 2 < NT) asm volatile("s_waitcnt vmcnt(6)" ::: "memory");
    else            asm volatile("s_waitcnt vmcnt(0)" ::: "memory");
    __builtin_amdgcn_s_barrier();
  }

  // ---- epilogue. C/D map col=lane&15, row=(lane>>4)*4+reg ----
  const float* bb = bias;
  u16* op = outp;
  int nofs = 0, Nout = N;
  bool sig = false;
  if (MODE == 4) {
    Nout = N >> 1;
    if (n0 >= Nout) { bb = bias2; op = outp2; nofs = Nout; sig = true; }
  }
  const int gmb = m0 + wr * 128 + qd * 4;
  const int gnb = n0 + wc * 64 + l16;
  float bc[4], wv4[4], bv4[4];
#pragma unroll
  for (int cf = 0; cf < 4; cf++) {
    int gn = gnb + cf * 16;
    bc[cf] = bb[gn - nofs];
    if (LNFOLD) { wv4[cf] = wvec[gn]; bv4[cf] = bvec[gn]; }
  }
#pragma unroll
  for (int rf = 0; rf < 8; rf++) {
#pragma unroll
    for (int r = 0; r < 4; r++) {
      const int gm = gmb + rf * 16 + r;
      float mu = 0.f, rv = 0.f;
      if (LNFOLD) { mu = s_mu[gm - m0]; rv = s_rv[gm - m0]; }
      float ps = 0.f, ps2 = 0.f;
#pragma unroll
      for (int cf = 0; cf < 4; cf++) {
        int gn = gnb + cf * 16;
        float vv = acc[rf][cf][r];
        if (LNFOLD) vv = rv * vv - rv * mu * wv4[cf] + bv4[cf] + bc[cf];
        else        vv += bc[cf];
        if (MODE == 2) vv = vv * fsigmoid(vv);
        if (MODE == 4 && sig) vv = fsigmoid(vv);
        size_t oidx = (size_t)gm * Nout + (gn - nofs);
        if (MODE == 3) vv += bf2f(res[oidx]);
        u16 rb = f2bf(vv);
        op[oidx] = rb;
        if (STATS) { float fv = bf2f(rb); ps += fv; ps2 += fv * fv; }
      }
      if (STATS) {
#pragma unroll
        for (int o = 1; o < 16; o <<= 1) {
          ps  += __shfl_xor(ps, o, 64);
          ps2 += __shfl_xor(ps2, o, 64);
        }
        if (l16 == 0) {
          atomicAdd(&stats_out[2 * gm], ps);
          atomicAdd(&stats_out[2 * gm + 1], ps2);
        }
      }
    }
  }
}

// ---------------- chunked linear-recurrence scan (u bf16, 4 ch/thread) ----------------
__global__ void k_scan_a(const bf16* __restrict__ u, const float* __restrict__ dl,
                         float* __restrict__ clast) {
  int t = threadIdx.x;            // 0..191
  int g = blockIdx.x;
  int d0 = t * 4;
  float dec[4], s[4] = {0.f, 0.f, 0.f, 0.f};
#pragma unroll
  for (int c = 0; c < 4; c++) dec[c] = fsigmoid(dl[d0 + c]);
  const ushort4* up = (const ushort4*)(u + (size_t)g * S_T * D_MOD) + t;
  for (int tt = 0; tt < S_T; tt++) {
    ushort4 uv = up[(size_t)tt * 192];
    s[0] = fmaf(dec[0], s[0], bf2f(uv.x));
    s[1] = fmaf(dec[1], s[1], bf2f(uv.y));
    s[2] = fmaf(dec[2], s[2], bf2f(uv.z));
    s[3] = fmaf(dec[3], s[3], bf2f(uv.w));
  }
#pragma unroll
  for (int c = 0; c < 4; c++) clast[(size_t)g * D_MOD + d0 + c] = s[c];
}

__global__ void k_scan_b(const float* __restrict__ clast, const float* __restrict__ dl,
                         float* __restrict__ carry) {
  int d = threadIdx.x;
  float decay = fsigmoid(dl[d]);
  float aT = decay;
#pragma unroll
  for (int i = 0; i < 6; i++) aT *= aT;   // decay^64
  float c = 0.f;
  for (int g = 0; g < S_G; g++) {
    carry[(size_t)g * D_MOD + d] = c;
    c = fmaf(aT, c, clast[(size_t)g * D_MOD + d]);
  }
}

__global__ void k_scan_c(const bf16* __restrict__ u, const float* __restrict__ dl,
                         const float* __restrict__ carry, bf16* __restrict__ gate_s) {
  int t = threadIdx.x;            // 0..191
  int g = blockIdx.x;
  int d0 = t * 4;
  float dec[4], s[4];
#pragma unroll
  for (int c = 0; c < 4; c++) {
    dec[c] = fsigmoid(dl[d0 + c]);
    s[c] = carry[(size_t)g * D_MOD + d0 + c];
  }
  const ushort4* up = (const ushort4*)(u + (size_t)g * S_T * D_MOD) + t;
  ushort4* gp = (ushort4*)(gate_s + (size_t)g * S_T * D_MOD) + t;
  for (int tt = 0; tt < S_T; tt++) {
    ushort4 uv = up[(size_t)tt * 192];
    ushort4 gv = gp[(size_t)tt * 192];
    s[0] = fmaf(dec[0], s[0], bf2f(uv.x));
    s[1] = fmaf(dec[1], s[1], bf2f(uv.y));
    s[2] = fmaf(dec[2], s[2], bf2f(uv.z));
    s[3] = fmaf(dec[3], s[3], bf2f(uv.w));
    ushort4 ov;
    ov.x = f2bf(s[0] * bf2f(gv.x));
    ov.y = f2bf(s[1] * bf2f(gv.y));
    ov.z = f2bf(s[2] * bf2f(gv.z));
    ov.w = f2bf(s[3] * bf2f(gv.w));
    gp[(size_t)tt * 192] = ov;
  }
}

// ---------------- final LN: x bf16 + precomputed stats -> f32 out ----------------
__global__ __launch_bounds__(256) void k_ln_final(const u16* __restrict__ x,
    const float* __restrict__ stats, const float* __restrict__ g,
    const float* __restrict__ b, float* __restrict__ outp) {
  int wv = threadIdx.x >> 6, lane = threadIdx.x & 63;
  int row = blockIdx.x * 4 + wv;
  float sv = stats[2 * row], sq = stats[2 * row + 1];
  float mu = sv * (1.0f / (float)D_MOD);
  float var = sq * (1.0f / (float)D_MOD) - mu * mu;
  float rv = 1.0f / sqrtf(var + EPSV);
  const ushort4* xr = (const ushort4*)(x + (size_t)row * D_MOD);
  const float4* g4 = (const float4*)g;
  const float4* b4 = (const float4*)b;
  float4* o4 = (float4*)(outp + (size_t)row * D_MOD);
#pragma unroll
  for (int j = 0; j < 3; j++) {
    int f = j * 64 + lane;
    ushort4 xv = xr[f];
    float4 gg = g4[f], bb = b4[f], ov;
    ov.x = (bf2f(xv.x) - mu) * rv * gg.x + bb.x;
    ov.y = (bf2f(xv.y) - mu) * rv * gg.y + bb.y;
    ov.z = (bf2f(xv.z) - mu) * rv * gg.z + bb.z;
    ov.w = (bf2f(xv.w) - mu) * rv * gg.w + bb.w;
    o4[f] = ov;
  }
}

extern "C" void kernel_launch(void* const* d_in, const int* in_sizes, int n_in,
                              void* d_out, int out_size, void* d_ws, size_t ws_size,
                              hipStream_t stream) {
  const float* nf     = (const float*)d_in[0];
  const float* W_proj = (const float*)d_in[1];
  const float* b_proj = (const float*)d_in[2];
  const float* ln_s_g = (const float*)d_in[3];
  const float* ln_s_b = (const float*)d_in[4];
  const float* W_in   = (const float*)d_in[5];
  const float* b_in   = (const float*)d_in[6];
  const float* W_gate = (const float*)d_in[7];
  const float* b_gate = (const float*)d_in[8];
  const float* W_out  = (const float*)d_in[9];
  const float* b_out  = (const float*)d_in[10];
  const float* dlogit = (const float*)d_in[11];
  const float* ln_f_g = (const float*)d_in[12];
  const float* ln_f_b = (const float*)d_in[13];
  const float* W_ff1  = (const float*)d_in[14];
  const float* b_ff1  = (const float*)d_in[15];
  const float* W_ff2  = (const float*)d_in[16];
  const float* b_ff2  = (const float*)d_in[17];
  const float* ln_o_g = (const float*)d_in[18];
  const float* ln_o_b = (const float*)d_in[19];
  (void)in_sizes; (void)n_in;

  char* ws = (char*)d_ws;
  size_t off = 0;
  auto alloc = [&](size_t bytes) -> char* {
    char* p = ws + off;
    off = (off + bytes + 255) & ~(size_t)255;
    return p;
  };
  const bool big = ws_size >= (160ull << 20);
  const size_t wmul = big ? N_LAYER : 1;

  u16*   x     = (u16*)alloc(2ull * L_TOK * D_MOD);        // residual stream, bf16 (25 MB)
  // shared region (50.3 MB): nfb (pre-loop) | u+gate (recurrence) | tb (FF)
  char*  ug    = alloc(2ull * L_TOK * D_FF);
  u16*   u     = (u16*)ug;
  u16*   gate  = (u16*)(ug + 2ull * L_TOK * D_MOD);
  u16*   tb    = (u16*)ug;
  u16*   nfb   = (u16*)ug;
  bf16*  WprojT= (bf16*)alloc(2ull * D_INP * D_MOD);
  bf16*  WigT  = (bf16*)alloc(2ull * wmul * (2 * D_MOD) * D_MOD);  // [g∘W_in^T ; g∘W_gate^T]
  bf16*  WoT   = (bf16*)alloc(2ull * wmul * D_MOD * D_MOD);
  bf16*  Wff1T = (bf16*)alloc(2ull * wmul * D_MOD * D_FF);
  bf16*  Wff2T = (bf16*)alloc(2ull * wmul * D_FF * D_MOD);
  float* clast = (float*)alloc(sizeof(float) * (size_t)S_G * D_MOD);
  float* carry = (float*)alloc(sizeof(float) * (size_t)S_G * D_MOD);
  // zeroed region: stats slots [17][16384][2] + fold vectors
  char*  zbase = alloc(0);
  float* stats = (float*)alloc(sizeof(float) * 17ull * L_TOK * 2);     // 2.23 MB
  float* wvig  = (float*)alloc(sizeof(float) * N_LAYER * 2 * D_MOD);   // g_s@[W_in|W_gate]
  float* bvig  = (float*)alloc(sizeof(float) * N_LAYER * 2 * D_MOD);
  float* wvf1  = (float*)alloc(sizeof(float) * N_LAYER * D_FF);        // g_f@W_ff1
  float* bvf1  = (float*)alloc(sizeof(float) * N_LAYER * D_FF);
  size_t zbytes = (size_t)((char*)ws + off - zbase);
  hipMemsetAsync(zbase, 0, zbytes, stream);

  const size_t DD = (size_t)D_MOD * D_MOD, DF = (size_t)D_MOD * D_FF;
  auto statslot = [&](int s) { return stats + (size_t)s * L_TOK * 2; };
  dim3 tb32(32, 8);
  k_f32_to_bf16v<<<(L_TOK * D_INP / 4 + 255) / 256, 256, 0, stream>>>(
      (const float4*)nf, (ushort4*)nfb, L_TOK * D_INP / 4);
  k_transpose_fold<false><<<dim3(D_MOD / 32, D_INP / 32, 1), tb32, 0, stream>>>(
      W_proj, WprojT, D_INP, D_MOD, 0, 0, nullptr, nullptr, nullptr, nullptr, 0);
  if (big) {
    k_transpose_fold<true><<<dim3(D_MOD / 32, D_MOD / 32, N_LAYER), tb32, 0, stream>>>(
        W_in,   WigT,      D_MOD, D_MOD, DD, 2 * DD, ln_s_g, ln_s_b, wvig,       bvig,       2 * D_MOD);
    k_transpose_fold<true><<<dim3(D_MOD / 32, D_MOD / 32, N_LAYER), tb32, 0, stream>>>(
        W_gate, WigT + DD, D_MOD, D_MOD, DD, 2 * DD, ln_s_g, ln_s_b, wvig + D_MOD, bvig + D_MOD, 2 * D_MOD);
    k_transpose_fold<false><<<dim3(D_MOD / 32, D_MOD / 32, N_LAYER), tb32, 0, stream>>>(
        W_out,  WoT,       D_MOD, D_MOD, DD, DD, nullptr, nullptr, nullptr, nullptr, 0);
    k_transpose_fold<true><<<dim3(D_FF / 32,  D_MOD / 32, N_LAYER), tb32, 0, stream>>>(
        W_ff1,  Wff1T,     D_MOD, D_FF,  DF, DF, ln_f_g, ln_f_b, wvf1, bvf1, D_FF);
    k_transpose_fold<false><<<dim3(D_MOD / 32, D_FF / 32,  N_LAYER), tb32, 0, stream>>>(
        W_ff2,  Wff2T,     D_FF,  D_MOD, DF, DF, nullptr, nullptr, nullptr, nullptr, 0);
  }

  // x = nf @ W_proj + b_proj  (bf16 out + stats slot 0)
  k_gemm256<0, false, true><<<64 * 3, 512, 0, stream>>>(
      (const short*)nfb, (const short*)WprojT, b_proj, nullptr, nullptr, nullptr,
      nullptr, statslot(0), nullptr, x, nullptr, D_MOD, D_INP, 3);

  for (int l = 0; l < N_LAYER; l++) {
    const bf16 *wigT, *woT, *wf1T, *wf2T;
    if (big) {
      wigT = WigT  + (size_t)l * 2 * DD;
      woT  = WoT   + (size_t)l * DD;
      wf1T = Wff1T + (size_t)l * DF;
      wf2T = Wff2T + (size_t)l * DF;
    } else {
      k_transpose_fold<true><<<dim3(D_MOD / 32, D_MOD / 32, 1), tb32, 0, stream>>>(
          W_in + (size_t)l * DD, WigT, D_MOD, D_MOD, 0, 0,
          ln_s_g + l * D_MOD, ln_s_b + l * D_MOD, wvig + (size_t)l * 2 * D_MOD, bvig + (size_t)l * 2 * D_MOD, 0);
      k_transpose_fold<true><<<dim3(D_MOD / 32, D_MOD / 32, 1), tb32, 0, stream>>>(
          W_gate + (size_t)l * DD, WigT + DD, D_MOD, D_MOD, 0, 0,
          ln_s_g + l * D_MOD, ln_s_b + l * D_MOD, wvig + (size_t)l * 2 * D_MOD + D_MOD, bvig + (size_t)l * 2 * D_MOD + D_MOD, 0);
      k_transpose_fold<false><<<dim3(D_MOD / 32, D_MOD / 32, 1), tb32, 0, stream>>>(
          W_out + (size_t)l * DD, WoT, D_MOD, D_MOD, 0, 0, nullptr, nullptr, nullptr, nullptr, 0);
      k_transpose_fold<true><<<dim3(D_FF / 32, D_MOD / 32, 1), tb32, 0, stream>>>(
          W_ff1 + (size_t)l * DF, Wff1T, D_MOD, D_FF, 0, 0,
          ln_f_g + l * D_MOD, ln_f_b + l * D_MOD, wvf1 + (size_t)l * D_FF, bvf1 + (size_t)l * D_FF, 0);
      k_transpose_fold<false><<<dim3(D_MOD / 32, D_FF / 32, 1), tb32, 0, stream>>>(
          W_ff2 + (size_t)l * DF, Wff2T, D_FF, D_MOD, 0, 0, nullptr, nullptr, nullptr, nullptr, 0);
      wigT = WigT; woT = WoT; wf1T = Wff1T; wf2T = Wff2T;
    }

    // fused LN_s + (u | gate) GEMM: A = x directly
    k_gemm256<4, true, false><<<64 * 6, 512, 0, stream>>>(
        (const short*)x, (const short*)wigT, b_in + l * D_MOD, b_gate + l * D_MOD,
        wvig + (size_t)l * 2 * D_MOD, bvig + (size_t)l * 2 * D_MOD,
        statslot(2 * l), nullptr, nullptr, u, gate, 2 * D_MOD, D_MOD, 6);
    // chunked scan; s*gate -> gate buffer (bf16)
    k_scan_a<<<S_G, 192, 0, stream>>>((const bf16*)u, dlogit + l * D_MOD, clast);
    k_scan_b<<<1, D_MOD, 0, stream>>>(clast, dlogit + l * D_MOD, carry);
    k_scan_c<<<S_G, 192, 0, stream>>>((const bf16*)u, dlogit + l * D_MOD, carry, (bf16*)gate);
    // x = x + sg @ W_out + b_out  (bf16 in-place + stats slot 2l+1)
    k_gemm256<3, false, true><<<64 * 3, 512, 0, stream>>>(
        (const short*)gate, (const short*)woT, b_out + l * D_MOD, nullptr, nullptr, nullptr,
        nullptr, statslot(2 * l + 1), x, x, nullptr, D_MOD, D_MOD, 3);
    // fused LN_f + FF1 (silu): A = x directly
    k_gemm256<2, true, false><<<64 * 6, 512, 0, stream>>>(
        (const short*)x, (const short*)wf1T, b_ff1 + l * D_FF, nullptr,
        wvf1 + (size_t)l * D_FF, bvf1 + (size_t)l * D_FF,
        statslot(2 * l + 1), nullptr, nullptr, tb, nullptr, D_FF, D_MOD, 6);
    // x = x + tb @ W_ff2 + b_ff2  (bf16 in-place + stats slot 2l+2)
    k_gemm256<3, false, true><<<64 * 3, 512, 0, stream>>>(
        (const short*)tb, (const short*)wf2T, b_ff2 + l * D_MOD, nullptr, nullptr, nullptr,
        nullptr, statslot(2 * l + 2), x, x, nullptr, D_MOD, D_FF, 3);
  }

  // out = LN_o(x) (f32) using stats slot 16
  k_ln_final<<<L_TOK / 4, 256, 0, stream>>>(x, statslot(2 * N_LAYER), ln_o_g, ln_o_b, (float*)d_out);
}

// Round 5
// 2304.841 us; speedup vs baseline: 1.1273x; 1.0846x over previous
//
#include <hip/hip_runtime.h>
#include <hip/hip_bf16.h>
#include <math.h>
#include <string.h>

#define L_TOK 16384
#define D_INP 256
#define D_MOD 768
#define D_FF  1536
#define N_LAYER 8
#define S_T 64
#define S_G 256
#define EPSV 1e-5f

typedef short bf16x8 __attribute__((ext_vector_type(8)));
typedef float f32x4 __attribute__((ext_vector_type(4)));
typedef __hip_bfloat16 bf16;
typedef unsigned int u32;
typedef unsigned short u16;

__device__ __forceinline__ float fsigmoid(float z) { return 1.0f / (1.0f + __expf(-z)); }

__device__ __forceinline__ u16 f2bf(float f) {
  __hip_bfloat16 h = __float2bfloat16(f);
  u16 r; memcpy(&r, &h, 2); return r;
}
__device__ __forceinline__ float bf2f(u16 v) {
  u32 x = ((u32)v) << 16; float f; memcpy(&f, &x, 4); return f;
}

// async global->LDS, 16B per lane. LDS dest = (wave-uniform base) + lane*16.
__device__ __forceinline__ void glds16(const short* g, short* l) {
  __builtin_amdgcn_global_load_lds(
      (const __attribute__((address_space(1))) unsigned int*)(g),
      (__attribute__((address_space(3))) unsigned int*)(l), 16, 0, 0);
}

// inline-asm ds_read_b128, opaque to the compiler's waitcnt pass: with counted
// vmcnt + raw s_barrier, compiler-visible LDS reads would trigger a conservative
// vmcnt(0) drain against outstanding global_load_lds (round-3 lesson). Completion
// is enforced manually: s_waitcnt lgkmcnt(0) + sched_barrier(0) before the MFMAs.
__device__ __forceinline__ bf16x8 dsr128(const char* base, int imm) {
  bf16x8 r;
  const __attribute__((address_space(3))) char* p =
      (const __attribute__((address_space(3))) char*)base;
  asm volatile("ds_read_b128 %0, %1 offset:%c2" : "=v"(r) : "v"(p), "i"(imm));
  return r;
}

// ---------------- f32 -> bf16, vectorized ----------------
__global__ void k_f32_to_bf16v(const float4* __restrict__ src, ushort4* __restrict__ dst, int n4) {
  int i = blockIdx.x * blockDim.x + threadIdx.x;
  if (i < n4) {
    float4 v = src[i];
    ushort4 o; o.x = f2bf(v.x); o.y = f2bf(v.y); o.z = f2bf(v.z); o.w = f2bf(v.w);
    dst[i] = o;
  }
}

// ------- transpose+convert (+optional LN-fold): src [z][R,C] f32 -> dst [z][C,R] bf16
template<bool FOLD>
__global__ void k_transpose_fold(const float* __restrict__ src, bf16* __restrict__ dst,
                                 int R, int C, size_t sstride, size_t dstride,
                                 const float* __restrict__ gv, const float* __restrict__ bv,
                                 float* __restrict__ wacc, float* __restrict__ bacc,
                                 int vstride) {
  __shared__ float tile[32][33];
  int z = blockIdx.z;
  const float* s = src + (size_t)z * sstride;
  bf16* d = dst + (size_t)z * dstride;
  int r0 = blockIdx.y * 32, c0 = blockIdx.x * 32;
  int tx = threadIdx.x, ty = threadIdx.y;
#pragma unroll
  for (int i = ty; i < 32; i += 8)
    tile[i][tx] = s[(size_t)(r0 + i) * C + (c0 + tx)];
  __syncthreads();
  float gk = 1.0f;
  if (FOLD) gk = gv[(size_t)z * R + r0 + tx];
#pragma unroll
  for (int i = ty; i < 32; i += 8) {
    float val = tile[tx][i];
    if (FOLD) val *= gk;
    d[(size_t)(c0 + i) * R + (r0 + tx)] = __float2bfloat16(val);
  }
  if (FOLD && ty == 0) {
    const float* gz = gv + (size_t)z * R + r0;
    const float* bz = bv + (size_t)z * R + r0;
    float s1 = 0.f, s2 = 0.f;
#pragma unroll 8
    for (int j = 0; j < 32; j++) {
      float wv = tile[j][tx];
      s1 += gz[j] * wv;
      s2 += bz[j] * wv;
    }
    atomicAdd(&wacc[(size_t)z * vstride + c0 + tx], s1);
    atomicAdd(&bacc[(size_t)z * vstride + c0 + tx], s2);
  }
}

// ---------------- bf16 MFMA GEMM: 128x128 tile, BK=32, 3 blocks/CU (TLP overlap) ----
// Round-0 structure (proven 69.4us @ N=1536) + T4 counted-vmcnt depth-2 prefetch:
// 3 LDS buffers; iter t reads buf[t%3], stages tile t+2 into buf[(t+2)%3] (the
// buffer tile t-1 vacated - safe: end-of-(t-1) barrier ordered all its reads
// before this iter's stage issue). End-of-iter wait = vmcnt(4): tile t+1's 4 glds
// (issued at t-1, ~2 iters of flight) must land; t+2's 4 stay in flight. Never
// vmcnt(0) mid-loop -> the m97-structure per-iter drain stall is removed while
// keeping 3-blocks/CU wave-level MFMA/VMEM overlap (m114).
// MODE: 0 bias; 2 silu; 3 bias+residual(bf16,in-place); 4 split u|gate.
// LNFOLD: A is raw residual x; val = rv*acc - rv*mu*wvec[gn] + bvec[gn] + bias.
// STATS: per-row sum/sumsq of written bf16 into stats_out (pre-zeroed).
template<int MODE, bool LNFOLD, bool STATS>
__global__ __launch_bounds__(256, 4) void k_gemm128(
    const short* __restrict__ A, const short* __restrict__ Bt,
    const float* __restrict__ bias, const float* __restrict__ bias2,
    const float* __restrict__ wvec, const float* __restrict__ bvec,
    const float* __restrict__ stats_in, float* __restrict__ stats_out,
    u16* __restrict__ res, u16* __restrict__ outp, u16* __restrict__ outp2,
    int N, int K, int ncol)
{
  __shared__ short As[3][128 * 32];
  __shared__ short Bs[3][128 * 32];
  __shared__ float s_mu[128], s_rv[128];
  const int tid = threadIdx.x;
  const int lane = tid & 63, w = tid >> 6;
  const int wr = w >> 1, wc = w & 1;
  const int l16 = lane & 15, qd = lane >> 4;

  const int b = blockIdx.x;
  const int xcd = b & 7, t = b >> 3;
  const int m0 = (xcd * 16 + t / ncol) * 128;
  const int n0 = (t % ncol) * 128;

  const int sr = lane >> 2, sc = lane & 3;
  const int ar = w * 32 + sr;
  const int acx = sc ^ ((ar >> 1) & 3);
  const short* ag0 = A  + (size_t)(m0 + ar) * K + acx * 8;
  const short* ag1 = ag0 + (size_t)16 * K;
  const short* bg0 = Bt + (size_t)(n0 + ar) * K + acx * 8;
  const short* bg1 = bg0 + (size_t)16 * K;

  auto stg = [&](int bi, int k0) {
    short* a0 = &As[bi][w * 1024];
    glds16(ag0 + k0, a0); glds16(ag1 + k0, a0 + 512);
    short* b0 = &Bs[bi][w * 1024];
    glds16(bg0 + k0, b0); glds16(bg1 + k0, b0 + 512);
  };

  const int fo = (qd ^ ((l16 >> 1) & 3)) * 8 + l16 * 32;

  // LN stats load issued first (oldest VMEM; compiler waits with a counted vmcnt,
  // never draining the staging queue)
  float sv = 0.f, sq = 0.f;
  if (LNFOLD && tid < 128) {
    sv = stats_in[2 * (m0 + tid)];
    sq = stats_in[2 * (m0 + tid) + 1];
  }

  const int NT = K >> 5;   // K is 256 or 768 -> NT >= 8
  // depth-2 prologue: tiles 0 and 1 (4 glds each per wave)
  stg(0, 0);
  stg(1, 32);

  if (LNFOLD && tid < 128) {
    float mu  = sv * (1.0f / (float)D_MOD);
    float var = sq * (1.0f / (float)D_MOD) - mu * mu;
    s_mu[tid] = mu;
    s_rv[tid] = 1.0f / sqrtf(var + EPSV);
  }

  f32x4 acc[4][4];
#pragma unroll
  for (int i = 0; i < 4; i++)
#pragma unroll
    for (int j = 0; j < 4; j++) acc[i][j] = (f32x4){0.f, 0.f, 0.f, 0.f};

  // tile 0 landed (our own oldest 4 glds; tile 1's 4 may stay in flight)
  asm volatile("s_waitcnt vmcnt(4)" ::: "memory");
  __builtin_amdgcn_s_barrier();

  int rd = 0;                       // rd = t % 3
  for (int t2 = 0; t2 < NT; ++t2) {
    const char* ab = (const char*)&As[rd][wr * 2048 + fo];
    const char* bb = (const char*)&Bs[rd][wc * 2048 + fo];
    bf16x8 af0 = dsr128(ab, 0),    af1 = dsr128(ab, 1024);
    bf16x8 af2 = dsr128(ab, 2048), af3 = dsr128(ab, 3072);
    bf16x8 bf0 = dsr128(bb, 0),    bf1 = dsr128(bb, 1024);
    bf16x8 bf2 = dsr128(bb, 2048), bf3 = dsr128(bb, 3072);
    if (t2 + 2 < NT) {
      int st = (rd == 0) ? 2 : rd - 1;   // (t+2) % 3
      stg(st, (t2 + 2) * 32);
    }
    asm volatile("s_waitcnt lgkmcnt(0)" ::: "memory");
    __builtin_amdgcn_sched_barrier(0);
    bf16x8 af[4] = {af0, af1, af2, af3};
    bf16x8 bfr[4] = {bf0, bf1, bf2, bf3};
#pragma unroll
    for (int rt = 0; rt < 4; rt++)
#pragma unroll
      for (int ct = 0; ct < 4; ct++)
        acc[rt][ct] = __builtin_amdgcn_mfma_f32_16x16x32_bf16(af[rt], bfr[ct], acc[rt][ct], 0, 0, 0);
    // tile t+1 must be fully landed before next iter reads it; keep t+2 in flight
    if (t2 + 2 < NT) asm volatile("s_waitcnt vmcnt(4)" ::: "memory");
    else             asm volatile("s_waitcnt vmcnt(0)" ::: "memory");
    __builtin_amdgcn_s_barrier();
    rd = (rd == 2) ? 0 : rd + 1;
  }

  // ---- epilogue. C/D map col=lane&15, row=(lane>>4)*4+reg ----
  const float* bb = bias;
  u16* op = outp;
  int nofs = 0, Nout = N;
  bool sig = false;
  if (MODE == 4) {
    Nout = N >> 1;
    if (n0 >= Nout) { bb = bias2; op = outp2; nofs = Nout; sig = true; }
  }
  const int gmb = m0 + wr * 64 + qd * 4;
  const int gnb = n0 + wc * 64 + l16;
  float bc[4], wv4[4], bv4[4];
#pragma unroll
  for (int ct = 0; ct < 4; ct++) {
    int gn = gnb + ct * 16;
    bc[ct] = bb[gn - nofs];
    if (LNFOLD) { wv4[ct] = wvec[gn]; bv4[ct] = bvec[gn]; }
  }
#pragma unroll
  for (int rt = 0; rt < 4; rt++) {
#pragma unroll
    for (int r = 0; r < 4; r++) {
      const int gm = gmb + rt * 16 + r;
      float mu = 0.f, rv = 0.f;
      if (LNFOLD) { mu = s_mu[gm - m0]; rv = s_rv[gm - m0]; }
      float ps = 0.f, ps2 = 0.f;
#pragma unroll
      for (int ct = 0; ct < 4; ct++) {
        int gn = gnb + ct * 16;
        float vv = acc[rt][ct][r];
        if (LNFOLD) vv = rv * vv - rv * mu * wv4[ct] + bv4[ct] + bc[ct];
        else        vv += bc[ct];
        if (MODE == 2) vv = vv * fsigmoid(vv);
        if (MODE == 4 && sig) vv = fsigmoid(vv);
        size_t oidx = (size_t)gm * Nout + (gn - nofs);
        if (MODE == 3) vv += bf2f(res[oidx]);
        u16 rb = f2bf(vv);
        op[oidx] = rb;
        if (STATS) { float fv = bf2f(rb); ps += fv; ps2 += fv * fv; }
      }
      if (STATS) {
#pragma unroll
        for (int o = 1; o < 16; o <<= 1) {
          ps  += __shfl_xor(ps, o, 64);
          ps2 += __shfl_xor(ps2, o, 64);
        }
        if (l16 == 0) {
          atomicAdd(&stats_out[2 * gm], ps);
          atomicAdd(&stats_out[2 * gm + 1], ps2);
        }
      }
    }
  }
}

// ---------------- chunked linear-recurrence scan (u bf16, 4 ch/thread) ----------------
__global__ void k_scan_a(const bf16* __restrict__ u, const float* __restrict__ dl,
                         float* __restrict__ clast) {
  int t = threadIdx.x;            // 0..191
  int g = blockIdx.x;
  int d0 = t * 4;
  float dec[4], s[4] = {0.f, 0.f, 0.f, 0.f};
#pragma unroll
  for (int c = 0; c < 4; c++) dec[c] = fsigmoid(dl[d0 + c]);
  const ushort4* up = (const ushort4*)(u + (size_t)g * S_T * D_MOD) + t;
  for (int tt = 0; tt < S_T; tt++) {
    ushort4 uv = up[(size_t)tt * 192];
    s[0] = fmaf(dec[0], s[0], bf2f(uv.x));
    s[1] = fmaf(dec[1], s[1], bf2f(uv.y));
    s[2] = fmaf(dec[2], s[2], bf2f(uv.z));
    s[3] = fmaf(dec[3], s[3], bf2f(uv.w));
  }
#pragma unroll
  for (int c = 0; c < 4; c++) clast[(size_t)g * D_MOD + d0 + c] = s[c];
}

__global__ void k_scan_b(const float* __restrict__ clast, const float* __restrict__ dl,
                         float* __restrict__ carry) {
  int d = threadIdx.x;
  float decay = fsigmoid(dl[d]);
  float aT = decay;
#pragma unroll
  for (int i = 0; i < 6; i++) aT *= aT;   // decay^64
  float c = 0.f;
  for (int g = 0; g < S_G; g++) {
    carry[(size_t)g * D_MOD + d] = c;
    c = fmaf(aT, c, clast[(size_t)g * D_MOD + d]);
  }
}

__global__ void k_scan_c(const bf16* __restrict__ u, const float* __restrict__ dl,
                         const float* __restrict__ carry, bf16* __restrict__ gate_s) {
  int t = threadIdx.x;            // 0..191
  int g = blockIdx.x;
  int d0 = t * 4;
  float dec[4], s[4];
#pragma unroll
  for (int c = 0; c < 4; c++) {
    dec[c] = fsigmoid(dl[d0 + c]);
    s[c] = carry[(size_t)g * D_MOD + d0 + c];
  }
  const ushort4* up = (const ushort4*)(u + (size_t)g * S_T * D_MOD) + t;
  ushort4* gp = (ushort4*)(gate_s + (size_t)g * S_T * D_MOD) + t;
  for (int tt = 0; tt < S_T; tt++) {
    ushort4 uv = up[(size_t)tt * 192];
    ushort4 gv = gp[(size_t)tt * 192];
    s[0] = fmaf(dec[0], s[0], bf2f(uv.x));
    s[1] = fmaf(dec[1], s[1], bf2f(uv.y));
    s[2] = fmaf(dec[2], s[2], bf2f(uv.z));
    s[3] = fmaf(dec[3], s[3], bf2f(uv.w));
    ushort4 ov;
    ov.x = f2bf(s[0] * bf2f(gv.x));
    ov.y = f2bf(s[1] * bf2f(gv.y));
    ov.z = f2bf(s[2] * bf2f(gv.z));
    ov.w = f2bf(s[3] * bf2f(gv.w));
    gp[(size_t)tt * 192] = ov;
  }
}

// ---------------- final LN: x bf16 + precomputed stats -> f32 out ----------------
__global__ __launch_bounds__(256) void k_ln_final(const u16* __restrict__ x,
    const float* __restrict__ stats, const float* __restrict__ g,
    const float* __restrict__ b, float* __restrict__ outp) {
  int wv = threadIdx.x >> 6, lane = threadIdx.x & 63;
  int row = blockIdx.x * 4 + wv;
  float sv = stats[2 * row], sq = stats[2 * row + 1];
  float mu = sv * (1.0f / (float)D_MOD);
  float var = sq * (1.0f / (float)D_MOD) - mu * mu;
  float rv = 1.0f / sqrtf(var + EPSV);
  const ushort4* xr = (const ushort4*)(x + (size_t)row * D_MOD);
  const float4* g4 = (const float4*)g;
  const float4* b4 = (const float4*)b;
  float4* o4 = (float4*)(outp + (size_t)row * D_MOD);
#pragma unroll
  for (int j = 0; j < 3; j++) {
    int f = j * 64 + lane;
    ushort4 xv = xr[f];
    float4 gg = g4[f], bb = b4[f], ov;
    ov.x = (bf2f(xv.x) - mu) * rv * gg.x + bb.x;
    ov.y = (bf2f(xv.y) - mu) * rv * gg.y + bb.y;
    ov.z = (bf2f(xv.z) - mu) * rv * gg.z + bb.z;
    ov.w = (bf2f(xv.w) - mu) * rv * gg.w + bb.w;
    o4[f] = ov;
  }
}

extern "C" void kernel_launch(void* const* d_in, const int* in_sizes, int n_in,
                              void* d_out, int out_size, void* d_ws, size_t ws_size,
                              hipStream_t stream) {
  const float* nf     = (const float*)d_in[0];
  const float* W_proj = (const float*)d_in[1];
  const float* b_proj = (const float*)d_in[2];
  const float* ln_s_g = (const float*)d_in[3];
  const float* ln_s_b = (const float*)d_in[4];
  const float* W_in   = (const float*)d_in[5];
  const float* b_in   = (const float*)d_in[6];
  const float* W_gate = (const float*)d_in[7];
  const float* b_gate = (const float*)d_in[8];
  const float* W_out  = (const float*)d_in[9];
  const float* b_out  = (const float*)d_in[10];
  const float* dlogit = (const float*)d_in[11];
  const float* ln_f_g = (const float*)d_in[12];
  const float* ln_f_b = (const float*)d_in[13];
  const float* W_ff1  = (const float*)d_in[14];
  const float* b_ff1  = (const float*)d_in[15];
  const float* W_ff2  = (const float*)d_in[16];
  const float* b_ff2  = (const float*)d_in[17];
  const float* ln_o_g = (const float*)d_in[18];
  const float* ln_o_b = (const float*)d_in[19];
  (void)in_sizes; (void)n_in;

  char* ws = (char*)d_ws;
  size_t off = 0;
  auto alloc = [&](size_t bytes) -> char* {
    char* p = ws + off;
    off = (off + bytes + 255) & ~(size_t)255;
    return p;
  };
  const bool big = ws_size >= (160ull << 20);
  const size_t wmul = big ? N_LAYER : 1;

  u16*   x     = (u16*)alloc(2ull * L_TOK * D_MOD);        // residual stream, bf16 (25 MB)
  // shared region (50.3 MB): nfb (pre-loop) | u+gate (recurrence) | tb (FF)
  char*  ug    = alloc(2ull * L_TOK * D_FF);
  u16*   u     = (u16*)ug;
  u16*   gate  = (u16*)(ug + 2ull * L_TOK * D_MOD);
  u16*   tb    = (u16*)ug;
  u16*   nfb   = (u16*)ug;
  bf16*  WprojT= (bf16*)alloc(2ull * D_INP * D_MOD);
  bf16*  WigT  = (bf16*)alloc(2ull * wmul * (2 * D_MOD) * D_MOD);  // [g∘W_in^T ; g∘W_gate^T]
  bf16*  WoT   = (bf16*)alloc(2ull * wmul * D_MOD * D_MOD);
  bf16*  Wff1T = (bf16*)alloc(2ull * wmul * D_MOD * D_FF);
  bf16*  Wff2T = (bf16*)alloc(2ull * wmul * D_FF * D_MOD);
  float* clast = (float*)alloc(sizeof(float) * (size_t)S_G * D_MOD);
  float* carry = (float*)alloc(sizeof(float) * (size_t)S_G * D_MOD);
  // zeroed region: stats slots [17][16384][2] + fold vectors
  char*  zbase = alloc(0);
  float* stats = (float*)alloc(sizeof(float) * 17ull * L_TOK * 2);     // 2.23 MB
  float* wvig  = (float*)alloc(sizeof(float) * N_LAYER * 2 * D_MOD);   // g_s@[W_in|W_gate]
  float* bvig  = (float*)alloc(sizeof(float) * N_LAYER * 2 * D_MOD);
  float* wvf1  = (float*)alloc(sizeof(float) * N_LAYER * D_FF);        // g_f@W_ff1
  float* bvf1  = (float*)alloc(sizeof(float) * N_LAYER * D_FF);
  size_t zbytes = (size_t)((char*)ws + off - zbase);
  hipMemsetAsync(zbase, 0, zbytes, stream);

  const size_t DD = (size_t)D_MOD * D_MOD, DF = (size_t)D_MOD * D_FF;
  auto statslot = [&](int s) { return stats + (size_t)s * L_TOK * 2; };
  dim3 tb32(32, 8);
  k_f32_to_bf16v<<<(L_TOK * D_INP / 4 + 255) / 256, 256, 0, stream>>>(
      (const float4*)nf, (ushort4*)nfb, L_TOK * D_INP / 4);
  k_transpose_fold<false><<<dim3(D_MOD / 32, D_INP / 32, 1), tb32, 0, stream>>>(
      W_proj, WprojT, D_INP, D_MOD, 0, 0, nullptr, nullptr, nullptr, nullptr, 0);
  if (big) {
    k_transpose_fold<true><<<dim3(D_MOD / 32, D_MOD / 32, N_LAYER), tb32, 0, stream>>>(
        W_in,   WigT,      D_MOD, D_MOD, DD, 2 * DD, ln_s_g, ln_s_b, wvig,       bvig,       2 * D_MOD);
    k_transpose_fold<true><<<dim3(D_MOD / 32, D_MOD / 32, N_LAYER), tb32, 0, stream>>>(
        W_gate, WigT + DD, D_MOD, D_MOD, DD, 2 * DD, ln_s_g, ln_s_b, wvig + D_MOD, bvig + D_MOD, 2 * D_MOD);
    k_transpose_fold<false><<<dim3(D_MOD / 32, D_MOD / 32, N_LAYER), tb32, 0, stream>>>(
        W_out,  WoT,       D_MOD, D_MOD, DD, DD, nullptr, nullptr, nullptr, nullptr, 0);
    k_transpose_fold<true><<<dim3(D_FF / 32,  D_MOD / 32, N_LAYER), tb32, 0, stream>>>(
        W_ff1,  Wff1T,     D_MOD, D_FF,  DF, DF, ln_f_g, ln_f_b, wvf1, bvf1, D_FF);
    k_transpose_fold<false><<<dim3(D_MOD / 32, D_FF / 32,  N_LAYER), tb32, 0, stream>>>(
        W_ff2,  Wff2T,     D_FF,  D_MOD, DF, DF, nullptr, nullptr, nullptr, nullptr, 0);
  }

  // x = nf @ W_proj + b_proj  (bf16 out + stats slot 0)
  k_gemm128<0, false, true><<<128 * 6, 256, 0, stream>>>(
      (const short*)nfb, (const short*)WprojT, b_proj, nullptr, nullptr, nullptr,
      nullptr, statslot(0), nullptr, x, nullptr, D_MOD, D_INP, 6);

  for (int l = 0; l < N_LAYER; l++) {
    const bf16 *wigT, *woT, *wf1T, *wf2T;
    if (big) {
      wigT = WigT  + (size_t)l * 2 * DD;
      woT  = WoT   + (size_t)l * DD;
      wf1T = Wff1T + (size_t)l * DF;
      wf2T = Wff2T + (size_t)l * DF;
    } else {
      k_transpose_fold<true><<<dim3(D_MOD / 32, D_MOD / 32, 1), tb32, 0, stream>>>(
          W_in + (size_t)l * DD, WigT, D_MOD, D_MOD, 0, 0,
          ln_s_g + l * D_MOD, ln_s_b + l * D_MOD, wvig + (size_t)l * 2 * D_MOD, bvig + (size_t)l * 2 * D_MOD, 0);
      k_transpose_fold<true><<<dim3(D_MOD / 32, D_MOD / 32, 1), tb32, 0, stream>>>(
          W_gate + (size_t)l * DD, WigT + DD, D_MOD, D_MOD, 0, 0,
          ln_s_g + l * D_MOD, ln_s_b + l * D_MOD, wvig + (size_t)l * 2 * D_MOD + D_MOD, bvig + (size_t)l * 2 * D_MOD + D_MOD, 0);
      k_transpose_fold<false><<<dim3(D_MOD / 32, D_MOD / 32, 1), tb32, 0, stream>>>(
          W_out + (size_t)l * DD, WoT, D_MOD, D_MOD, 0, 0, nullptr, nullptr, nullptr, nullptr, 0);
      k_transpose_fold<true><<<dim3(D_FF / 32, D_MOD / 32, 1), tb32, 0, stream>>>(
          W_ff1 + (size_t)l * DF, Wff1T, D_MOD, D_FF, 0, 0,
          ln_f_g + l * D_MOD, ln_f_b + l * D_MOD, wvf1 + (size_t)l * D_FF, bvf1 + (size_t)l * D_FF, 0);
      k_transpose_fold<false><<<dim3(D_MOD / 32, D_FF / 32, 1), tb32, 0, stream>>>(
          W_ff2 + (size_t)l * DF, Wff2T, D_FF, D_MOD, 0, 0, nullptr, nullptr, nullptr, nullptr, 0);
      wigT = WigT; woT = WoT; wf1T = Wff1T; wf2T = Wff2T;
    }

    // fused LN_s + (u | gate) GEMM: A = x directly
    k_gemm128<4, true, false><<<128 * 12, 256, 0, stream>>>(
        (const short*)x, (const short*)wigT, b_in + l * D_MOD, b_gate + l * D_MOD,
        wvig + (size_t)l * 2 * D_MOD, bvig + (size_t)l * 2 * D_MOD,
        statslot(2 * l), nullptr, nullptr, u, gate, 2 * D_MOD, D_MOD, 12);
    // chunked scan; s*gate -> gate buffer (bf16)
    k_scan_a<<<S_G, 192, 0, stream>>>((const bf16*)u, dlogit + l * D_MOD, clast);
    k_scan_b<<<1, D_MOD, 0, stream>>>(clast, dlogit + l * D_MOD, carry);
    k_scan_c<<<S_G, 192, 0, stream>>>((const bf16*)u, dlogit + l * D_MOD, carry, (bf16*)gate);
    // x = x + sg @ W_out + b_out  (bf16 in-place + stats slot 2l+1)
    k_gemm128<3, false, true><<<128 * 6, 256, 0, stream>>>(
        (const short*)gate, (const short*)woT, b_out + l * D_MOD, nullptr, nullptr, nullptr,
        nullptr, statslot(2 * l + 1), x, x, nullptr, D_MOD, D_MOD, 6);
    // fused LN_f + FF1 (silu): A = x directly
    k_gemm128<2, true, false><<<128 * 12, 256, 0, stream>>>(
        (const short*)x, (const short*)wf1T, b_ff1 + l * D_FF, nullptr,
        wvf1 + (size_t)l * D_FF, bvf1 + (size_t)l * D_FF,
        statslot(2 * l + 1), nullptr, nullptr, tb, nullptr, D_FF, D_MOD, 12);
    // x = x + tb @ W_ff2 + b_ff2  (bf16 in-place + stats slot 2l+2)
    k_gemm128<3, false, true><<<128 * 6, 256, 0, stream>>>(
        (const short*)tb, (const short*)wf2T, b_ff2 + l * D_MOD, nullptr, nullptr, nullptr,
        nullptr, statslot(2 * l + 2), x, x, nullptr, D_MOD, D_FF, 6);
  }

  // out = LN_o(x) (f32) using stats slot 16
  k_ln_final<<<L_TOK / 4, 256, 0, stream>>>(x, statslot(2 * N_LAYER), ln_o_g, ln_o_b, (float*)d_out);
}